// Round 11
// baseline (2012.999 us; speedup 1.0000x reference)
//
#include <hip/hip_runtime.h>
#include <stdint.h>

#define NB 8
#define NN 4096
#define NP 1024
#define NSAMP 32
#define CIN 64
#define C3 128
#define XS 20
#define SENT_DONE 0x00C0FFEEu

typedef float v2f __attribute__((ext_vector_type(2)));

__device__ __forceinline__ float lo2f(unsigned int u) { return __uint_as_float(u << 16); }
__device__ __forceinline__ float hi2f(unsigned int u) { return __uint_as_float(u & 0xffff0000u); }
__device__ __forceinline__ unsigned short f2b(float f) {
  unsigned int u = __float_as_uint(f);
  unsigned int r = u + 0x7fffu + ((u >> 16) & 1u);
  return (unsigned short)(r >> 16);
}
__device__ __forceinline__ unsigned int packbf(float a, float b) {
  return (unsigned int)f2b(a) | ((unsigned int)f2b(b) << 16);
}

#define FMAXD(v, ctrl)                                                     \
  do {                                                                     \
    int _x = __float_as_int(v);                                            \
    int _m = __builtin_amdgcn_update_dpp(_x, _x, (ctrl), 0xf, 0xf, false); \
    (v) = fmaxf((v), __int_as_float(_m));                                  \
  } while (0)

// ---- Kernel 1: 2-wave FPS (blocks 0..7) + ballast --------------------------
// Wave w owns points [w*2048, (w+1)*2048), lane L owns 32 contiguous. Sync =
// one b64 record post + poll of the single partner slot (record IS the flag,
// parity double-buffered). Waves 2..3 and blocks 8..255: pk-FMA clock ballast
// gated on global sentinels (hint-only; data correctness never depends on it).
__global__ __launch_bounds__(256, 1) void fps_kernel(
    const float* __restrict__ xyz, unsigned short* __restrict__ fps_g,
    float* __restrict__ out_xyz, unsigned int* __restrict__ sent) {
#pragma clang fp contract(off)
  const int blk = blockIdx.x;
  const int tid = threadIdx.x;
  if (blk >= NB) {  // ---------------- external ballast
    v2f a[8];
#pragma unroll
    for (int i = 0; i < 8; ++i) {
      float base = 1.0f + (float)(tid & 15) * 1e-6f + (float)i * 1e-7f;
      a[i] = (v2f){base, base + 1e-7f};
    }
    const v2f c1 = (v2f){1.0000001f, 1.0000001f};
    const v2f c2 = (v2f){1e-9f, 1e-9f};
    for (int r = 0; r < 400000; ++r) {
#pragma unroll
      for (int u = 0; u < 2; ++u)
#pragma unroll
        for (int i = 0; i < 8; ++i) a[i] = a[i] * c1 + c2;
      if ((r & 127) == 0) {
        unsigned ok = 1;
        if ((tid & 63) == 0) {
#pragma unroll
          for (int bb = 0; bb < NB; ++bb)
            ok &= (__hip_atomic_load(&sent[bb], __ATOMIC_RELAXED,
                                     __HIP_MEMORY_SCOPE_AGENT) == SENT_DONE)
                      ? 1u : 0u;
        }
        if (__ballot(ok != 0) & 1ull) break;
      }
    }
    float s = 0.f;
#pragma unroll
    for (int i = 0; i < 8; ++i) s += a[i].x + a[i].y;
    if (s == 123.456f) fps_g[0] = 0;  // never true
    return;
  }
  // ---------------- FPS block
  __shared__ float sx[NN], sy[NN], sz[NN];
  __shared__ __align__(16) unsigned long long slotmem[2][2];
  __shared__ unsigned short scidx[NP];
  const int b = blk;
  const float* xb = xyz + (size_t)b * NN * 3;
  for (int i = tid; i < NN; i += 256) {
    sx[i] = xb[3 * i + 0];
    sy[i] = xb[3 * i + 1];
    sz[i] = xb[3 * i + 2];
  }
  if (tid < 4) ((unsigned long long*)slotmem)[tid] = 0ull;
  if (tid == 0) scidx[0] = 0;
  __syncthreads();  // last barrier in this kernel
  if (tid >= 128) {  // waves 2..3: in-block ballast (exits via sent[b])
    v2f a[8];
#pragma unroll
    for (int i = 0; i < 8; ++i) {
      float base = 1.0f + (float)(tid & 15) * 1e-6f + (float)i * 1e-7f;
      a[i] = (v2f){base, base + 1e-7f};
    }
    const v2f c1 = (v2f){1.0000001f, 1.0000001f};
    const v2f c2 = (v2f){1e-9f, 1e-9f};
    for (int r = 0; r < 400000; ++r) {
#pragma unroll
      for (int u = 0; u < 2; ++u)
#pragma unroll
        for (int i = 0; i < 8; ++i) a[i] = a[i] * c1 + c2;
      if ((r & 127) == 0) {
        unsigned ok = 1;
        if ((tid & 63) == 0)
          ok = (__hip_atomic_load(&sent[b], __ATOMIC_RELAXED,
                                  __HIP_MEMORY_SCOPE_AGENT) == SENT_DONE)
                   ? 1u : 0u;
        if (__ballot(ok != 0) & 1ull) break;
      }
    }
    float s = 0.f;
#pragma unroll
    for (int i = 0; i < 8; ++i) s += a[i].x + a[i].y;
    if (s == 123.456f) fps_g[0] = 0;
    return;
  }
#if __has_builtin(__builtin_amdgcn_s_setprio)
  __builtin_amdgcn_s_setprio(3);
#endif
  const int lane = tid & 63;
  const int wv = tid >> 6;          // 0 or 1
  const int pbase = wv * 2048 + lane * 32;
  v2f px[16], py[16], pz[16], dd[16];
#pragma unroll
  for (int i = 0; i < 16; ++i) {
    int i0 = pbase + 2 * i;
    px[i] = (v2f){sx[i0], sx[i0 + 1]};
    py[i] = (v2f){sy[i0], sy[i0 + 1]};
    pz[i] = (v2f){sz[i0], sz[i0 + 1]};
    dd[i] = (v2f){1e10f, 1e10f};
  }
  float qx = sx[0], qy = sy[0], qz = sz[0];
  for (int k = 1; k < NP; ++k) {
    v2f q2x = (v2f){qx, qx};
    v2f q2y = (v2f){qy, qy};
    v2f q2z = (v2f){qz, qz};
#pragma unroll
    for (int i = 0; i < 16; ++i) {
      v2f dx = px[i] - q2x;
      v2f dy = py[i] - q2y;
      v2f dz = pz[i] - q2z;
      v2f xx = dx * dx;
      v2f yy = dy * dy;
      v2f zz = dz * dz;
      v2f s = xx + yy;
      v2f d = s + zz;  // per-element np order, contract off
      dd[i] = __builtin_elementwise_min(dd[i], d);
    }
    // intra-thread argmax over 32 (strict >, left/lower index wins ties)
    float v1[16]; int j1[16];
#pragma unroll
    for (int i = 0; i < 16; ++i) {
      bool g = dd[i].y > dd[i].x;
      v1[i] = g ? dd[i].y : dd[i].x;
      j1[i] = 2 * i + (g ? 1 : 0);
    }
    float v2a[8]; int j2a[8];
#pragma unroll
    for (int i = 0; i < 8; ++i) {
      bool g = v1[2 * i + 1] > v1[2 * i];
      v2a[i] = g ? v1[2 * i + 1] : v1[2 * i];
      j2a[i] = g ? j1[2 * i + 1] : j1[2 * i];
    }
    float v3[4]; int j3[4];
#pragma unroll
    for (int i = 0; i < 4; ++i) {
      bool g = v2a[2 * i + 1] > v2a[2 * i];
      v3[i] = g ? v2a[2 * i + 1] : v2a[2 * i];
      j3[i] = g ? j2a[2 * i + 1] : j2a[2 * i];
    }
    float v4[2]; int j4[2];
#pragma unroll
    for (int i = 0; i < 2; ++i) {
      bool g = v3[2 * i + 1] > v3[2 * i];
      v4[i] = g ? v3[2 * i + 1] : v3[2 * i];
      j4[i] = g ? j3[2 * i + 1] : j3[2 * i];
    }
    bool g0 = v4[1] > v4[0];
    float bestv = g0 ? v4[1] : v4[0];
    int gi = pbase + (g0 ? j4[1] : j4[0]);
    // wave64 max via DPP, winner = lowest lane (== lowest index)
    float m = bestv;
    FMAXD(m, 0x111); FMAXD(m, 0x112); FMAXD(m, 0x114);
    FMAXD(m, 0x118); FMAXD(m, 0x142); FMAXD(m, 0x143);
    float wmax = __int_as_float(__builtin_amdgcn_readlane(__float_as_int(m), 63));
    unsigned long long ball = __ballot(bestv == wmax);
    int wl = __ffsll((long long)ball) - 1;
    int widx = __builtin_amdgcn_readlane(gi, wl);
    unsigned long long rec =
        ((unsigned long long)(((unsigned)k << 12) | (unsigned)widx) << 32) |
        (unsigned long long)__float_as_uint(wmax);
    unsigned long long* slp = &slotmem[k & 1][0];
    if (lane == 0) slp[wv] = rec;
    asm volatile("" ::: "memory");
    unsigned long long prec;
    for (;;) {
      prec = slp[1 - wv];
      if ((unsigned)(prec >> 44) == (unsigned)k) break;
      asm volatile("" ::: "memory");
    }
    unsigned long long r0 = wv ? prec : rec;  // wave0-side record (lower idx)
    unsigned long long r1 = wv ? rec : prec;  // wave1-side record
    float v0 = __uint_as_float((unsigned)r0);
    float vv1 = __uint_as_float((unsigned)r1);
    bool g = vv1 > v0;  // strict: wave0 (lower index) wins ties
    int wi = g ? (int)((r1 >> 32) & 0xFFFu) : (int)((r0 >> 32) & 0xFFFu);
    qx = sx[wi]; qy = sy[wi]; qz = sz[wi];
    if (tid == 0) scidx[k] = (unsigned short)wi;
  }
  // wave0 -> wave1 handoff (scidx visibility) via tag-1024 record
  if (wv == 0) {
    __threadfence_block();
    if (lane == 0)
      slotmem[0][0] = ((unsigned long long)(1024u << 12) << 32);
    asm volatile("" ::: "memory");
  } else {
    for (;;) {
      unsigned long long t = slotmem[0][0];
      if ((unsigned)(t >> 44) >= 1024u) break;
      asm volatile("" ::: "memory");
    }
    asm volatile("" ::: "memory");
  }
  for (int i = tid; i < NP; i += 128) {
    int id = scidx[i];
    out_xyz[((size_t)b * NP + i) * 3 + 0] = sx[id];
    out_xyz[((size_t)b * NP + i) * 3 + 1] = sy[id];
    out_xyz[((size_t)b * NP + i) * 3 + 2] = sz[id];
    fps_g[b * NP + i] = (unsigned short)id;
  }
  if (tid == 0)
    __hip_atomic_store(&sent[b], SENT_DONE, __ATOMIC_RELAXED,
                       __HIP_MEMORY_SCOPE_AGENT);
}

// ---- Kernel 2: fused ballq + gather + MLP(67->64->64->128) + max -----------
// Block = 8 centers. Phase 0: each wave runs the exact ball-query scan for 2
// centers, indices land in LDS sgq (no global gidx buffer). Phase 1+: R10 mlp.
__global__ __launch_bounds__(256) void mlp_kernel(
    const float* __restrict__ xyz, const float* __restrict__ points,
    const unsigned short* __restrict__ fps_idx,
    const float* __restrict__ W0, const float* __restrict__ b0,
    const float* __restrict__ g0, const float* __restrict__ be0,
    const float* __restrict__ W1, const float* __restrict__ b1,
    const float* __restrict__ g1, const float* __restrict__ be1,
    const float* __restrict__ W2, const float* __restrict__ b2,
    const float* __restrict__ g2, const float* __restrict__ be2,
    float* __restrict__ out_feat) {
  __shared__ __align__(16) float wbuf[4352];
  __shared__ __align__(16) unsigned int xpk[8 * 68 * XS];
  __shared__ float prm[768];
  __shared__ unsigned short sgq[8][NSAMP];
  const int tid = threadIdx.x;
  // ---- phase 0: ball query for this block's 8 centers (2 per wave)
  {
#pragma clang fp contract(off)
    const int lane = tid & 63;
    const int wvid = tid >> 6;
#pragma unroll 1
    for (int cc = 2 * wvid; cc < 2 * wvid + 2; ++cc) {
      const int sgg = blockIdx.x * 8 + cc;
      const int b = sgg >> 10, s = sgg & 1023;
      const float* xb = xyz + (size_t)b * NN * 3;
      const int ci = (int)fps_idx[b * NP + s] & (NN - 1);
      const float cx = xb[ci * 3 + 0];
      const float cy = xb[ci * 3 + 1];
      const float cz = xb[ci * 3 + 2];
      const float nn = (cx * cx + cy * cy) + cz * cz;
      const float r2 = 0.04f;
      int total = 0;
      int first = -1;
      for (int c = 0; c < NN / 64 && total < NSAMP; ++c) {
        int i = (c << 6) + lane;
        float x = xb[i * 3 + 0];
        float y = xb[i * 3 + 1];
        float z = xb[i * 3 + 2];
        float pp = (x * x + y * y) + z * z;
        float dt = (x * cx + y * cy) + z * cz;
        float sq = (nn + pp) - 2.0f * dt;  // exact ref formula; self-dist == 0
        bool inb = !(sq > r2);
        unsigned long long m = __ballot(inb);
        if (first < 0 && m) first = (c << 6) + (__ffsll((unsigned long long)m) - 1);
        int before = __popcll(m & ((1ull << lane) - 1ull));
        int slot = total + before;
        if (inb && slot < NSAMP) sgq[cc][slot] = (unsigned short)i;
        total += (int)__popcll(m);
      }
      int cnt = total < NSAMP ? total : NSAMP;
      unsigned short fill = (unsigned short)(first < 0 ? 0 : first);
      if (lane >= cnt && lane < NSAMP) sgq[cc][lane] = fill;
    }
  }
  __syncthreads();
  // ---- phase 1: params + gather + W0 staging (R10 layout)
  const float bnsc = 1.0f / sqrtf(1.001f);
  if (tid < 64) {
    prm[tid] = b0[tid];       prm[64 + tid] = g0[tid] * bnsc;  prm[128 + tid] = be0[tid];
    prm[192 + tid] = b1[tid]; prm[256 + tid] = g1[tid] * bnsc; prm[320 + tid] = be1[tid];
  }
  if (tid < 128) {
    prm[384 + tid] = b2[tid]; prm[512 + tid] = g2[tid] * bnsc; prm[640 + tid] = be2[tid];
  }
  if (tid < 128) {
    const int cbg = tid >> 4, r2 = tid & 15;
    const int sgg = blockIdx.x * 8 + cbg;
    const int bg = sgg >> 10, sg = sgg & 1023;
    const int i0 = (int)sgq[cbg][2 * r2] & (NN - 1);
    const int i1 = (int)sgq[cbg][2 * r2 + 1] & (NN - 1);
    const int ci = (int)fps_idx[bg * NP + sg] & (NN - 1);
    const float* xb = xyz + (size_t)bg * NN * 3;
    unsigned int* xc = &xpk[(cbg * 68) * XS + r2];
    const float cx = xb[ci * 3], cy = xb[ci * 3 + 1], cz = xb[ci * 3 + 2];
    xc[0 * XS] = packbf(xb[i0 * 3] - cx,     xb[i1 * 3] - cx);
    xc[1 * XS] = packbf(xb[i0 * 3 + 1] - cy, xb[i1 * 3 + 1] - cy);
    xc[2 * XS] = packbf(xb[i0 * 3 + 2] - cz, xb[i1 * 3 + 2] - cz);
    const float4* p0 = (const float4*)(points + ((size_t)bg * NN + i0) * CIN);
    const float4* p1 = (const float4*)(points + ((size_t)bg * NN + i1) * CIN);
#pragma unroll 4
    for (int kk = 0; kk < 16; ++kk) {
      float4 a = p0[kk], c = p1[kk];
      xc[(3 + 4 * kk) * XS] = packbf(a.x, c.x);
      xc[(4 + 4 * kk) * XS] = packbf(a.y, c.y);
      xc[(5 + 4 * kk) * XS] = packbf(a.z, c.z);
      xc[(6 + 4 * kk) * XS] = packbf(a.w, c.w);
    }
  } else {
    for (int i = tid - 128; i < 67 * 64; i += 128) wbuf[i] = W0[i];
  }
  const int cb = tid >> 5, rg = (tid >> 3) & 3, cg = tid & 7;
  const int sgc = blockIdx.x * 8 + cb;
  const int bc = sgc >> 10, sc = sgc & 1023;
  const unsigned int* xrow = &xpk[(cb * 68) * XS + rg * 4];
  float acc[64];
  auto kstep = [&](int k) {
    uint4 xp = *(const uint4*)(xrow + k * XS);
    float xr[8] = {lo2f(xp.x), hi2f(xp.x), lo2f(xp.y), hi2f(xp.y),
                   lo2f(xp.z), hi2f(xp.z), lo2f(xp.w), hi2f(xp.w)};
    float4 wa = *(const float4*)&wbuf[k * 64 + cg * 8];
    float4 wc = *(const float4*)&wbuf[k * 64 + cg * 8 + 4];
#pragma unroll
    for (int r = 0; r < 8; ++r) {
      acc[r * 8 + 0] = fmaf(xr[r], wa.x, acc[r * 8 + 0]);
      acc[r * 8 + 1] = fmaf(xr[r], wa.y, acc[r * 8 + 1]);
      acc[r * 8 + 2] = fmaf(xr[r], wa.z, acc[r * 8 + 2]);
      acc[r * 8 + 3] = fmaf(xr[r], wa.w, acc[r * 8 + 3]);
      acc[r * 8 + 4] = fmaf(xr[r], wc.x, acc[r * 8 + 4]);
      acc[r * 8 + 5] = fmaf(xr[r], wc.y, acc[r * 8 + 5]);
      acc[r * 8 + 6] = fmaf(xr[r], wc.z, acc[r * 8 + 6]);
      acc[r * 8 + 7] = fmaf(xr[r], wc.w, acc[r * 8 + 7]);
    }
  };
  auto hwrite = [&](int pofs) {
#pragma unroll
    for (int c = 0; c < 8; ++c) {
      int cl = cg * 8 + c;
      float bia = prm[pofs + cl], gg = prm[pofs + 64 + cl], bb = prm[pofs + 128 + cl];
      unsigned int* hc = &xpk[(cb * 68 + cl) * XS + rg * 4];
#pragma unroll
      for (int i = 0; i < 4; ++i) {
        float za = acc[(2 * i) * 8 + c] + bia;
        za = za > 0.f ? za : 0.f;
        za = za * gg + bb;
        float zb = acc[(2 * i + 1) * 8 + c] + bia;
        zb = zb > 0.f ? zb : 0.f;
        zb = zb * gg + bb;
        hc[i] = packbf(za, zb);
      }
    }
  };
  __syncthreads();
#pragma unroll
  for (int i = 0; i < 64; ++i) acc[i] = 0.f;
#pragma unroll 2
  for (int k = 0; k < 67; ++k) kstep(k);
  __syncthreads();
  hwrite(0);
  for (int i = tid; i < 64 * 64; i += 256) wbuf[i] = W1[i];
  __syncthreads();
#pragma unroll
  for (int i = 0; i < 64; ++i) acc[i] = 0.f;
#pragma unroll 2
  for (int k = 0; k < 64; ++k) kstep(k);
  __syncthreads();
  hwrite(192);
  for (int i = tid; i < 64 * 64; i += 256) wbuf[i] = W2[(i >> 6) * C3 + (i & 63)];
  __syncthreads();
  float* outp = out_feat + (size_t)(bc * NP + sc) * C3;
#pragma unroll 1
  for (int half = 0; half < 2; ++half) {
    if (half) {
      __syncthreads();
      for (int i = tid; i < 64 * 64; i += 256)
        wbuf[i] = W2[(i >> 6) * C3 + 64 + (i & 63)];
      __syncthreads();
    }
#pragma unroll
    for (int i = 0; i < 64; ++i) acc[i] = 0.f;
#pragma unroll 2
    for (int k = 0; k < 64; ++k) kstep(k);
    float vout[8];
#pragma unroll
    for (int c = 0; c < 8; ++c) {
      int cl = half * 64 + cg * 8 + c;
      float bia = prm[384 + cl], gg = prm[512 + cl], bb = prm[640 + cl];
      float mmax = -3.4e38f;
#pragma unroll
      for (int r = 0; r < 8; ++r) {
        float z = acc[r * 8 + c] + bia;
        z = z > 0.f ? z : 0.f;
        z = z * gg + bb;
        mmax = fmaxf(mmax, z);
      }
      mmax = fmaxf(mmax, __shfl_xor(mmax, 8, 64));
      mmax = fmaxf(mmax, __shfl_xor(mmax, 16, 64));
      vout[c] = mmax;
    }
    if (rg == 0) {
      *(float4*)(outp + half * 64 + cg * 8) =
          make_float4(vout[0], vout[1], vout[2], vout[3]);
      *(float4*)(outp + half * 64 + cg * 8 + 4) =
          make_float4(vout[4], vout[5], vout[6], vout[7]);
    }
  }
}

extern "C" void kernel_launch(void* const* d_in, const int* in_sizes, int n_in,
                              void* d_out, int out_size, void* d_ws, size_t ws_size,
                              hipStream_t stream) {
  const float* xyz = (const float*)d_in[0];
  const float* points = (const float*)d_in[1];
  const float* W0 = (const float*)d_in[2];
  const float* b0 = (const float*)d_in[3];
  const float* g0 = (const float*)d_in[4];
  const float* be0 = (const float*)d_in[5];
  const float* W1 = (const float*)d_in[6];
  const float* b1 = (const float*)d_in[7];
  const float* g1 = (const float*)d_in[8];
  const float* be1 = (const float*)d_in[9];
  const float* W2 = (const float*)d_in[10];
  const float* b2 = (const float*)d_in[11];
  const float* g2 = (const float*)d_in[12];
  const float* be2 = (const float*)d_in[13];
  float* out = (float*)d_out;
  unsigned short* fps = (unsigned short*)d_ws;                 // 16 KB
  unsigned int* sent = (unsigned int*)((char*)d_ws + 16 * 1024);
  fps_kernel<<<256, 256, 0, stream>>>(xyz, fps, out, sent);
  mlp_kernel<<<(NB * NP) / 8, 256, 0, stream>>>(xyz, points, fps,
                                                W0, b0, g0, be0, W1, b1, g1, be1,
                                                W2, b2, g2, be2,
                                                out + (size_t)NB * NP * 3);
}

// Round 12
// 1137.102 us; speedup vs baseline: 1.7703x; 1.7703x over previous
//
#include <hip/hip_runtime.h>
#include <stdint.h>

#define NB 8
#define NN 4096
#define NP 1024
#define NSAMP 32
#define CIN 64
#define C3 128
#define XS 20
#define SENT_DONE 0x00C0FFEEu
#define GRID1 64  // 8 fps blocks + 56 ballast blocks

typedef float v2f __attribute__((ext_vector_type(2)));

__device__ __forceinline__ float lo2f(unsigned int u) { return __uint_as_float(u << 16); }
__device__ __forceinline__ float hi2f(unsigned int u) { return __uint_as_float(u & 0xffff0000u); }
__device__ __forceinline__ unsigned short f2b(float f) {
  unsigned int u = __float_as_uint(f);
  unsigned int r = u + 0x7fffu + ((u >> 16) & 1u);
  return (unsigned short)(r >> 16);
}
__device__ __forceinline__ unsigned int packbf(float a, float b) {
  return (unsigned int)f2b(a) | ((unsigned int)f2b(b) << 16);
}

#define FMAXD(v, ctrl)                                                     \
  do {                                                                     \
    int _x = __float_as_int(v);                                            \
    int _m = __builtin_amdgcn_update_dpp(_x, _x, (ctrl), 0xf, 0xf, false); \
    (v) = fmaxf((v), __int_as_float(_m));                                  \
  } while (0)

// ---- Kernel 1: FPS (blocks 0..7; 4 waves, 16 pts/thread) + light ballast ---
// Exact R10 FPS protocol (measured best: 890 us): per-wave b64 record
// {val | (k<<12|idx)<<32} in parity double-buffered LDS slots; record IS the
// flag; poll = two independent 16B LDS loads. R12 change: ballast shrunk to
// 56 blocks (power-limited-DVFS theory).
__global__ __launch_bounds__(256, 1) void fps_kernel(
    const float* __restrict__ xyz, unsigned short* __restrict__ fps_g,
    float* __restrict__ out_xyz, unsigned int* __restrict__ sent) {
#pragma clang fp contract(off)
  const int blk = blockIdx.x;
  const int tid = threadIdx.x;
  if (blk >= NB) {  // ---------------- ballast: dense pk-FMA, rare checks
    v2f a[8];
#pragma unroll
    for (int i = 0; i < 8; ++i) {
      float base = 1.0f + (float)(tid & 15) * 1e-6f + (float)i * 1e-7f;
      a[i] = (v2f){base, base + 1e-7f};
    }
    const v2f c1 = (v2f){1.0000001f, 1.0000001f};
    const v2f c2 = (v2f){1e-9f, 1e-9f};
    for (int r = 0; r < 200000; ++r) {
#pragma unroll
      for (int u = 0; u < 2; ++u)
#pragma unroll
        for (int i = 0; i < 8; ++i) a[i] = a[i] * c1 + c2;
      if ((r & 127) == 0) {
        unsigned ok = 1;
        if ((tid & 63) == 0) {
#pragma unroll
          for (int bb = 0; bb < NB; ++bb)
            ok &= (__hip_atomic_load(&sent[bb], __ATOMIC_RELAXED,
                                     __HIP_MEMORY_SCOPE_AGENT) == SENT_DONE)
                      ? 1u : 0u;
        }
        if (__ballot(ok != 0) & 1ull) break;
      }
    }
    float s = 0.f;
#pragma unroll
    for (int i = 0; i < 8; ++i) s += a[i].x + a[i].y;
    if (s == 123.456f) fps_g[0] = 0;  // never true
    return;
  }
  // ---------------- FPS path
#if __has_builtin(__builtin_amdgcn_s_setprio)
  __builtin_amdgcn_s_setprio(3);
#endif
  __shared__ float sx[NN], sy[NN], sz[NN];
  __shared__ __align__(16) unsigned long long slotmem[2][4];
  __shared__ unsigned short scidx[NP];
  const int b = blk;
  const int lane = tid & 63;
  const int wv = tid >> 6;
  const float* xb = xyz + (size_t)b * NN * 3;
  for (int i = tid; i < NN; i += 256) {
    sx[i] = xb[3 * i + 0];
    sy[i] = xb[3 * i + 1];
    sz[i] = xb[3 * i + 2];
  }
  if (tid < 8) ((unsigned long long*)slotmem)[tid] = 0ull;  // k-field 0
  if (tid == 0) scidx[0] = 0;
  __syncthreads();
  v2f px[8], py[8], pz[8], dd[8];
#pragma unroll
  for (int i = 0; i < 8; ++i) {
    int i0 = tid * 16 + 2 * i;
    px[i] = (v2f){sx[i0], sx[i0 + 1]};
    py[i] = (v2f){sy[i0], sy[i0 + 1]};
    pz[i] = (v2f){sz[i0], sz[i0 + 1]};
    dd[i] = (v2f){1e10f, 1e10f};
  }
  float qx = sx[0], qy = sy[0], qz = sz[0];
  for (int k = 1; k < NP; ++k) {
    v2f q2x = (v2f){qx, qx};
    v2f q2y = (v2f){qy, qy};
    v2f q2z = (v2f){qz, qz};
#pragma unroll
    for (int i = 0; i < 8; ++i) {
      v2f dx = px[i] - q2x;
      v2f dy = py[i] - q2y;
      v2f dz = pz[i] - q2z;
      v2f xx = dx * dx;
      v2f yy = dy * dy;
      v2f zz = dz * dz;
      v2f s = xx + yy;
      v2f d = s + zz;  // per-element np order, contract off
      dd[i] = __builtin_elementwise_min(dd[i], d);
    }
    // intra-thread argmax over 16 (first-index ties via strict >, left=lower)
    float v1[8]; int j1[8];
#pragma unroll
    for (int i = 0; i < 8; ++i) {
      bool g = dd[i].y > dd[i].x;
      v1[i] = g ? dd[i].y : dd[i].x;
      j1[i] = 2 * i + (g ? 1 : 0);
    }
    float v2a[4]; int j2a[4];
#pragma unroll
    for (int i = 0; i < 4; ++i) {
      bool g = v1[2 * i + 1] > v1[2 * i];
      v2a[i] = g ? v1[2 * i + 1] : v1[2 * i];
      j2a[i] = g ? j1[2 * i + 1] : j1[2 * i];
    }
    float v3[2]; int j3[2];
#pragma unroll
    for (int i = 0; i < 2; ++i) {
      bool g = v2a[2 * i + 1] > v2a[2 * i];
      v3[i] = g ? v2a[2 * i + 1] : v2a[2 * i];
      j3[i] = g ? j2a[2 * i + 1] : j2a[2 * i];
    }
    bool g0 = v3[1] > v3[0];
    float bestv = g0 ? v3[1] : v3[0];
    int gi = tid * 16 + (g0 ? j3[1] : j3[0]);
    // wave max via DPP
    float m = bestv;
    FMAXD(m, 0x111); FMAXD(m, 0x112); FMAXD(m, 0x114);
    FMAXD(m, 0x118); FMAXD(m, 0x142); FMAXD(m, 0x143);
    float wmax = __int_as_float(__builtin_amdgcn_readlane(__float_as_int(m), 63));
    unsigned long long ball = __ballot(bestv == wmax);
    int wl = __ffsll((long long)ball) - 1;  // lowest lane == lowest index
    int widx = __builtin_amdgcn_readlane(gi, wl);
    unsigned long long rec =
        ((unsigned long long)(((unsigned)k << 12) | (unsigned)widx) << 32) |
        (unsigned long long)__float_as_uint(wmax);
    unsigned long long* sl = &slotmem[k & 1][0];
    if (lane == 0) sl[wv] = rec;
    asm volatile("" ::: "memory");
    // poll: two independent 16B loads per spin
    unsigned long long s0, s1, s2, s3;
    for (;;) {
      ulonglong2 pa = *(const ulonglong2*)(sl);
      ulonglong2 pb = *(const ulonglong2*)(sl + 2);
      s0 = pa.x; s1 = pa.y; s2 = pb.x; s3 = pb.y;
      if ((unsigned)(s0 >> 44) == (unsigned)k &&
          (unsigned)(s1 >> 44) == (unsigned)k &&
          (unsigned)(s2 >> 44) == (unsigned)k &&
          (unsigned)(s3 >> 44) == (unsigned)k)
        break;
      asm volatile("" ::: "memory");
    }
    float bv = __uint_as_float((unsigned)s0);
    int wi = (int)((s0 >> 32) & 0xFFFu);
    {
      float v = __uint_as_float((unsigned)s1);
      int iw = (int)((s1 >> 32) & 0xFFFu);
      bool g = v > bv; bv = g ? v : bv; wi = g ? iw : wi;
    }
    {
      float v = __uint_as_float((unsigned)s2);
      int iw = (int)((s2 >> 32) & 0xFFFu);
      bool g = v > bv; bv = g ? v : bv; wi = g ? iw : wi;
    }
    {
      float v = __uint_as_float((unsigned)s3);
      int iw = (int)((s3 >> 32) & 0xFFFu);
      bool g = v > bv; bv = g ? v : bv; wi = g ? iw : wi;
    }
    qx = sx[wi]; qy = sy[wi]; qz = sz[wi];  // broadcast reads
    if (tid == 0) scidx[k] = (unsigned short)wi;
  }
  __syncthreads();
  for (int i = tid; i < NP; i += 256) {
    int id = scidx[i];
    out_xyz[((size_t)b * NP + i) * 3 + 0] = sx[id];
    out_xyz[((size_t)b * NP + i) * 3 + 1] = sy[id];
    out_xyz[((size_t)b * NP + i) * 3 + 2] = sz[id];
    fps_g[b * NP + i] = (unsigned short)id;
  }
  __syncthreads();
  if (tid == 0)
    __hip_atomic_store(&sent[b], SENT_DONE, __ATOMIC_RELAXED,
                       __HIP_MEMORY_SCOPE_AGENT);
}

// ---- Kernel 2: fused ballq + gather + MLP(67->64->64->128) + max -----------
__global__ __launch_bounds__(256) void mlp_kernel(
    const float* __restrict__ xyz, const float* __restrict__ points,
    const unsigned short* __restrict__ fps_idx,
    const float* __restrict__ W0, const float* __restrict__ b0,
    const float* __restrict__ g0, const float* __restrict__ be0,
    const float* __restrict__ W1, const float* __restrict__ b1,
    const float* __restrict__ g1, const float* __restrict__ be1,
    const float* __restrict__ W2, const float* __restrict__ b2,
    const float* __restrict__ g2, const float* __restrict__ be2,
    float* __restrict__ out_feat) {
  __shared__ __align__(16) float wbuf[4352];
  __shared__ __align__(16) unsigned int xpk[8 * 68 * XS];
  __shared__ float prm[768];
  __shared__ unsigned short sgq[8][NSAMP];
  const int tid = threadIdx.x;
  // ---- phase 0: ball query for this block's 8 centers (2 per wave)
  {
#pragma clang fp contract(off)
    const int lane = tid & 63;
    const int wvid = tid >> 6;
#pragma unroll 1
    for (int cc = 2 * wvid; cc < 2 * wvid + 2; ++cc) {
      const int sgg = blockIdx.x * 8 + cc;
      const int b = sgg >> 10, s = sgg & 1023;
      const float* xb = xyz + (size_t)b * NN * 3;
      const int ci = (int)fps_idx[b * NP + s] & (NN - 1);
      const float cx = xb[ci * 3 + 0];
      const float cy = xb[ci * 3 + 1];
      const float cz = xb[ci * 3 + 2];
      const float nn = (cx * cx + cy * cy) + cz * cz;
      const float r2 = 0.04f;
      int total = 0;
      int first = -1;
      for (int c = 0; c < NN / 64 && total < NSAMP; ++c) {
        int i = (c << 6) + lane;
        float x = xb[i * 3 + 0];
        float y = xb[i * 3 + 1];
        float z = xb[i * 3 + 2];
        float pp = (x * x + y * y) + z * z;
        float dt = (x * cx + y * cy) + z * cz;
        float sq = (nn + pp) - 2.0f * dt;  // exact ref formula; self-dist == 0
        bool inb = !(sq > r2);
        unsigned long long m = __ballot(inb);
        if (first < 0 && m) first = (c << 6) + (__ffsll((unsigned long long)m) - 1);
        int before = __popcll(m & ((1ull << lane) - 1ull));
        int slot = total + before;
        if (inb && slot < NSAMP) sgq[cc][slot] = (unsigned short)i;
        total += (int)__popcll(m);
      }
      int cnt = total < NSAMP ? total : NSAMP;
      unsigned short fill = (unsigned short)(first < 0 ? 0 : first);
      if (lane >= cnt && lane < NSAMP) sgq[cc][lane] = fill;
    }
  }
  __syncthreads();
  // ---- phase 1: params + gather + W0 staging
  const float bnsc = 1.0f / sqrtf(1.001f);
  if (tid < 64) {
    prm[tid] = b0[tid];       prm[64 + tid] = g0[tid] * bnsc;  prm[128 + tid] = be0[tid];
    prm[192 + tid] = b1[tid]; prm[256 + tid] = g1[tid] * bnsc; prm[320 + tid] = be1[tid];
  }
  if (tid < 128) {
    prm[384 + tid] = b2[tid]; prm[512 + tid] = g2[tid] * bnsc; prm[640 + tid] = be2[tid];
  }
  if (tid < 128) {
    const int cbg = tid >> 4, r2 = tid & 15;
    const int sgg = blockIdx.x * 8 + cbg;
    const int bg = sgg >> 10, sg = sgg & 1023;
    const int i0 = (int)sgq[cbg][2 * r2] & (NN - 1);
    const int i1 = (int)sgq[cbg][2 * r2 + 1] & (NN - 1);
    const int ci = (int)fps_idx[bg * NP + sg] & (NN - 1);
    const float* xb = xyz + (size_t)bg * NN * 3;
    unsigned int* xc = &xpk[(cbg * 68) * XS + r2];
    const float cx = xb[ci * 3], cy = xb[ci * 3 + 1], cz = xb[ci * 3 + 2];
    xc[0 * XS] = packbf(xb[i0 * 3] - cx,     xb[i1 * 3] - cx);
    xc[1 * XS] = packbf(xb[i0 * 3 + 1] - cy, xb[i1 * 3 + 1] - cy);
    xc[2 * XS] = packbf(xb[i0 * 3 + 2] - cz, xb[i1 * 3 + 2] - cz);
    const float4* p0 = (const float4*)(points + ((size_t)bg * NN + i0) * CIN);
    const float4* p1 = (const float4*)(points + ((size_t)bg * NN + i1) * CIN);
#pragma unroll 4
    for (int kk = 0; kk < 16; ++kk) {
      float4 a = p0[kk], c = p1[kk];
      xc[(3 + 4 * kk) * XS] = packbf(a.x, c.x);
      xc[(4 + 4 * kk) * XS] = packbf(a.y, c.y);
      xc[(5 + 4 * kk) * XS] = packbf(a.z, c.z);
      xc[(6 + 4 * kk) * XS] = packbf(a.w, c.w);
    }
  } else {
    for (int i = tid - 128; i < 67 * 64; i += 128) wbuf[i] = W0[i];
  }
  const int cb = tid >> 5, rg = (tid >> 3) & 3, cg = tid & 7;
  const int sgc = blockIdx.x * 8 + cb;
  const int bc = sgc >> 10, sc = sgc & 1023;
  const unsigned int* xrow = &xpk[(cb * 68) * XS + rg * 4];
  float acc[64];
  auto kstep = [&](int k) {
    uint4 xp = *(const uint4*)(xrow + k * XS);
    float xr[8] = {lo2f(xp.x), hi2f(xp.x), lo2f(xp.y), hi2f(xp.y),
                   lo2f(xp.z), hi2f(xp.z), lo2f(xp.w), hi2f(xp.w)};
    float4 wa = *(const float4*)&wbuf[k * 64 + cg * 8];
    float4 wc = *(const float4*)&wbuf[k * 64 + cg * 8 + 4];
#pragma unroll
    for (int r = 0; r < 8; ++r) {
      acc[r * 8 + 0] = fmaf(xr[r], wa.x, acc[r * 8 + 0]);
      acc[r * 8 + 1] = fmaf(xr[r], wa.y, acc[r * 8 + 1]);
      acc[r * 8 + 2] = fmaf(xr[r], wa.z, acc[r * 8 + 2]);
      acc[r * 8 + 3] = fmaf(xr[r], wa.w, acc[r * 8 + 3]);
      acc[r * 8 + 4] = fmaf(xr[r], wc.x, acc[r * 8 + 4]);
      acc[r * 8 + 5] = fmaf(xr[r], wc.y, acc[r * 8 + 5]);
      acc[r * 8 + 6] = fmaf(xr[r], wc.z, acc[r * 8 + 6]);
      acc[r * 8 + 7] = fmaf(xr[r], wc.w, acc[r * 8 + 7]);
    }
  };
  auto hwrite = [&](int pofs) {
#pragma unroll
    for (int c = 0; c < 8; ++c) {
      int cl = cg * 8 + c;
      float bia = prm[pofs + cl], gg = prm[pofs + 64 + cl], bb = prm[pofs + 128 + cl];
      unsigned int* hc = &xpk[(cb * 68 + cl) * XS + rg * 4];
#pragma unroll
      for (int i = 0; i < 4; ++i) {
        float za = acc[(2 * i) * 8 + c] + bia;
        za = za > 0.f ? za : 0.f;
        za = za * gg + bb;
        float zb = acc[(2 * i + 1) * 8 + c] + bia;
        zb = zb > 0.f ? zb : 0.f;
        zb = zb * gg + bb;
        hc[i] = packbf(za, zb);
      }
    }
  };
  __syncthreads();
#pragma unroll
  for (int i = 0; i < 64; ++i) acc[i] = 0.f;
#pragma unroll 2
  for (int k = 0; k < 67; ++k) kstep(k);
  __syncthreads();
  hwrite(0);
  for (int i = tid; i < 64 * 64; i += 256) wbuf[i] = W1[i];
  __syncthreads();
#pragma unroll
  for (int i = 0; i < 64; ++i) acc[i] = 0.f;
#pragma unroll 2
  for (int k = 0; k < 64; ++k) kstep(k);
  __syncthreads();
  hwrite(192);
  for (int i = tid; i < 64 * 64; i += 256) wbuf[i] = W2[(i >> 6) * C3 + (i & 63)];
  __syncthreads();
  float* outp = out_feat + (size_t)(bc * NP + sc) * C3;
#pragma unroll 1
  for (int half = 0; half < 2; ++half) {
    if (half) {
      __syncthreads();
      for (int i = tid; i < 64 * 64; i += 256)
        wbuf[i] = W2[(i >> 6) * C3 + 64 + (i & 63)];
      __syncthreads();
    }
#pragma unroll
    for (int i = 0; i < 64; ++i) acc[i] = 0.f;
#pragma unroll 2
    for (int k = 0; k < 64; ++k) kstep(k);
    float vout[8];
#pragma unroll
    for (int c = 0; c < 8; ++c) {
      int cl = half * 64 + cg * 8 + c;
      float bia = prm[384 + cl], gg = prm[512 + cl], bb = prm[640 + cl];
      float mmax = -3.4e38f;
#pragma unroll
      for (int r = 0; r < 8; ++r) {
        float z = acc[r * 8 + c] + bia;
        z = z > 0.f ? z : 0.f;
        z = z * gg + bb;
        mmax = fmaxf(mmax, z);
      }
      mmax = fmaxf(mmax, __shfl_xor(mmax, 8, 64));
      mmax = fmaxf(mmax, __shfl_xor(mmax, 16, 64));
      vout[c] = mmax;
    }
    if (rg == 0) {
      *(float4*)(outp + half * 64 + cg * 8) =
          make_float4(vout[0], vout[1], vout[2], vout[3]);
      *(float4*)(outp + half * 64 + cg * 8 + 4) =
          make_float4(vout[4], vout[5], vout[6], vout[7]);
    }
  }
}

extern "C" void kernel_launch(void* const* d_in, const int* in_sizes, int n_in,
                              void* d_out, int out_size, void* d_ws, size_t ws_size,
                              hipStream_t stream) {
  const float* xyz = (const float*)d_in[0];
  const float* points = (const float*)d_in[1];
  const float* W0 = (const float*)d_in[2];
  const float* b0 = (const float*)d_in[3];
  const float* g0 = (const float*)d_in[4];
  const float* be0 = (const float*)d_in[5];
  const float* W1 = (const float*)d_in[6];
  const float* b1 = (const float*)d_in[7];
  const float* g1 = (const float*)d_in[8];
  const float* be1 = (const float*)d_in[9];
  const float* W2 = (const float*)d_in[10];
  const float* b2 = (const float*)d_in[11];
  const float* g2 = (const float*)d_in[12];
  const float* be2 = (const float*)d_in[13];
  float* out = (float*)d_out;
  unsigned short* fps = (unsigned short*)d_ws;                 // 16 KB
  unsigned int* sent = (unsigned int*)((char*)d_ws + 16 * 1024);
  fps_kernel<<<GRID1, 256, 0, stream>>>(xyz, fps, out, sent);
  mlp_kernel<<<(NB * NP) / 8, 256, 0, stream>>>(xyz, points, fps,
                                                W0, b0, g0, be0, W1, b1, g1, be1,
                                                W2, b2, g2, be2,
                                                out + (size_t)NB * NP * 3);
}

// Round 13
// 1093.664 us; speedup vs baseline: 1.8406x; 1.0397x over previous
//
#include <hip/hip_runtime.h>
#include <stdint.h>

#define NB 8
#define NN 4096
#define NP 1024
#define NSAMP 32
#define CIN 64
#define C3 128
#define XS 20
#define SENT_DONE 0x00C0FFEEu
#define GRID1 64  // 8 fps blocks + 56 ballast blocks

typedef float v2f __attribute__((ext_vector_type(2)));

__device__ __forceinline__ float lo2f(unsigned int u) { return __uint_as_float(u << 16); }
__device__ __forceinline__ float hi2f(unsigned int u) { return __uint_as_float(u & 0xffff0000u); }
__device__ __forceinline__ unsigned short f2b(float f) {
  unsigned int u = __float_as_uint(f);
  unsigned int r = u + 0x7fffu + ((u >> 16) & 1u);
  return (unsigned short)(r >> 16);
}
__device__ __forceinline__ unsigned int packbf(float a, float b) {
  return (unsigned int)f2b(a) | ((unsigned int)f2b(b) << 16);
}

#define FMAXD(v, ctrl)                                                     \
  do {                                                                     \
    int _x = __float_as_int(v);                                            \
    int _m = __builtin_amdgcn_update_dpp(_x, _x, (ctrl), 0xf, 0xf, false); \
    (v) = fmaxf((v), __int_as_float(_m));                                  \
  } while (0)

// ---- Kernel 1: FPS (blocks 0..7; 4 waves, 16 pts/thread) + light ballast ---
// Measured-best structure (R12, 860 us): per-wave b64 record
// {val | (k<<12|idx)<<32} in parity double-buffered LDS slots; record IS the
// flag; poll = two independent 16B LDS loads; 56 ballast blocks.
__global__ __launch_bounds__(256, 1) void fps_kernel(
    const float* __restrict__ xyz, unsigned short* __restrict__ fps_g,
    float* __restrict__ out_xyz, unsigned int* __restrict__ sent) {
#pragma clang fp contract(off)
  const int blk = blockIdx.x;
  const int tid = threadIdx.x;
  if (blk >= NB) {  // ---------------- ballast: dense pk-FMA, rare checks
    v2f a[8];
#pragma unroll
    for (int i = 0; i < 8; ++i) {
      float base = 1.0f + (float)(tid & 15) * 1e-6f + (float)i * 1e-7f;
      a[i] = (v2f){base, base + 1e-7f};
    }
    const v2f c1 = (v2f){1.0000001f, 1.0000001f};
    const v2f c2 = (v2f){1e-9f, 1e-9f};
    for (int r = 0; r < 200000; ++r) {
#pragma unroll
      for (int u = 0; u < 2; ++u)
#pragma unroll
        for (int i = 0; i < 8; ++i) a[i] = a[i] * c1 + c2;
      if ((r & 127) == 0) {
        unsigned ok = 1;
        if ((tid & 63) == 0) {
#pragma unroll
          for (int bb = 0; bb < NB; ++bb)
            ok &= (__hip_atomic_load(&sent[bb], __ATOMIC_RELAXED,
                                     __HIP_MEMORY_SCOPE_AGENT) == SENT_DONE)
                      ? 1u : 0u;
        }
        if (__ballot(ok != 0) & 1ull) break;
      }
    }
    float s = 0.f;
#pragma unroll
    for (int i = 0; i < 8; ++i) s += a[i].x + a[i].y;
    if (s == 123.456f) fps_g[0] = 0;  // never true
    return;
  }
  // ---------------- FPS path
#if __has_builtin(__builtin_amdgcn_s_setprio)
  __builtin_amdgcn_s_setprio(3);
#endif
  __shared__ float sx[NN], sy[NN], sz[NN];
  __shared__ __align__(16) unsigned long long slotmem[2][4];
  __shared__ unsigned short scidx[NP];
  const int b = blk;
  const int lane = tid & 63;
  const int wv = tid >> 6;
  const float* xb = xyz + (size_t)b * NN * 3;
  for (int i = tid; i < NN; i += 256) {
    sx[i] = xb[3 * i + 0];
    sy[i] = xb[3 * i + 1];
    sz[i] = xb[3 * i + 2];
  }
  if (tid < 8) ((unsigned long long*)slotmem)[tid] = 0ull;  // k-field 0
  if (tid == 0) scidx[0] = 0;
  __syncthreads();
  v2f px[8], py[8], pz[8], dd[8];
#pragma unroll
  for (int i = 0; i < 8; ++i) {
    int i0 = tid * 16 + 2 * i;
    px[i] = (v2f){sx[i0], sx[i0 + 1]};
    py[i] = (v2f){sy[i0], sy[i0 + 1]};
    pz[i] = (v2f){sz[i0], sz[i0 + 1]};
    dd[i] = (v2f){1e10f, 1e10f};
  }
  float qx = sx[0], qy = sy[0], qz = sz[0];
  for (int k = 1; k < NP; ++k) {
    v2f q2x = (v2f){qx, qx};
    v2f q2y = (v2f){qy, qy};
    v2f q2z = (v2f){qz, qz};
#pragma unroll
    for (int i = 0; i < 8; ++i) {
      v2f dx = px[i] - q2x;
      v2f dy = py[i] - q2y;
      v2f dz = pz[i] - q2z;
      v2f xx = dx * dx;
      v2f yy = dy * dy;
      v2f zz = dz * dz;
      v2f s = xx + yy;
      v2f d = s + zz;  // per-element np order, contract off
      dd[i] = __builtin_elementwise_min(dd[i], d);
    }
    // intra-thread argmax over 16 (first-index ties via strict >, left=lower)
    float v1[8]; int j1[8];
#pragma unroll
    for (int i = 0; i < 8; ++i) {
      bool g = dd[i].y > dd[i].x;
      v1[i] = g ? dd[i].y : dd[i].x;
      j1[i] = 2 * i + (g ? 1 : 0);
    }
    float v2a[4]; int j2a[4];
#pragma unroll
    for (int i = 0; i < 4; ++i) {
      bool g = v1[2 * i + 1] > v1[2 * i];
      v2a[i] = g ? v1[2 * i + 1] : v1[2 * i];
      j2a[i] = g ? j1[2 * i + 1] : j1[2 * i];
    }
    float v3[2]; int j3[2];
#pragma unroll
    for (int i = 0; i < 2; ++i) {
      bool g = v2a[2 * i + 1] > v2a[2 * i];
      v3[i] = g ? v2a[2 * i + 1] : v2a[2 * i];
      j3[i] = g ? j2a[2 * i + 1] : j2a[2 * i];
    }
    bool g0 = v3[1] > v3[0];
    float bestv = g0 ? v3[1] : v3[0];
    int gi = tid * 16 + (g0 ? j3[1] : j3[0]);
    // wave max via DPP
    float m = bestv;
    FMAXD(m, 0x111); FMAXD(m, 0x112); FMAXD(m, 0x114);
    FMAXD(m, 0x118); FMAXD(m, 0x142); FMAXD(m, 0x143);
    float wmax = __int_as_float(__builtin_amdgcn_readlane(__float_as_int(m), 63));
    unsigned long long ball = __ballot(bestv == wmax);
    int wl = __ffsll((long long)ball) - 1;  // lowest lane == lowest index
    int widx = __builtin_amdgcn_readlane(gi, wl);
    unsigned long long rec =
        ((unsigned long long)(((unsigned)k << 12) | (unsigned)widx) << 32) |
        (unsigned long long)__float_as_uint(wmax);
    unsigned long long* sl = &slotmem[k & 1][0];
    if (lane == 0) sl[wv] = rec;
    asm volatile("" ::: "memory");
    // poll: two independent 16B loads per spin
    unsigned long long s0, s1, s2, s3;
    for (;;) {
      ulonglong2 pa = *(const ulonglong2*)(sl);
      ulonglong2 pb = *(const ulonglong2*)(sl + 2);
      s0 = pa.x; s1 = pa.y; s2 = pb.x; s3 = pb.y;
      if ((unsigned)(s0 >> 44) == (unsigned)k &&
          (unsigned)(s1 >> 44) == (unsigned)k &&
          (unsigned)(s2 >> 44) == (unsigned)k &&
          (unsigned)(s3 >> 44) == (unsigned)k)
        break;
      asm volatile("" ::: "memory");
    }
    float bv = __uint_as_float((unsigned)s0);
    int wi = (int)((s0 >> 32) & 0xFFFu);
    {
      float v = __uint_as_float((unsigned)s1);
      int iw = (int)((s1 >> 32) & 0xFFFu);
      bool g = v > bv; bv = g ? v : bv; wi = g ? iw : wi;
    }
    {
      float v = __uint_as_float((unsigned)s2);
      int iw = (int)((s2 >> 32) & 0xFFFu);
      bool g = v > bv; bv = g ? v : bv; wi = g ? iw : wi;
    }
    {
      float v = __uint_as_float((unsigned)s3);
      int iw = (int)((s3 >> 32) & 0xFFFu);
      bool g = v > bv; bv = g ? v : bv; wi = g ? iw : wi;
    }
    qx = sx[wi]; qy = sy[wi]; qz = sz[wi];  // broadcast reads
    if (tid == 0) scidx[k] = (unsigned short)wi;
  }
  __syncthreads();
  for (int i = tid; i < NP; i += 256) {
    int id = scidx[i];
    out_xyz[((size_t)b * NP + i) * 3 + 0] = sx[id];
    out_xyz[((size_t)b * NP + i) * 3 + 1] = sy[id];
    out_xyz[((size_t)b * NP + i) * 3 + 2] = sz[id];
    fps_g[b * NP + i] = (unsigned short)id;
  }
  __syncthreads();
  if (tid == 0)
    __hip_atomic_store(&sent[b], SENT_DONE, __ATOMIC_RELAXED,
                       __HIP_MEMORY_SCOPE_AGENT);
}

// ---- Kernel 2: ball query (one wave per center; standalone — R10) ----------
__global__ __launch_bounds__(256) void ballq_kernel(
    const float* __restrict__ xyz, const unsigned short* __restrict__ fps_idx,
    unsigned short* __restrict__ gidx) {
#pragma clang fp contract(off)
  const int tid = threadIdx.x;
  const int gid = blockIdx.x * 4 + (tid >> 6);
  const int lane = tid & 63;
  const int b = gid >> 10;
  const int s = gid & 1023;
  const float* xb = xyz + (size_t)b * NN * 3;
  const int ci = (int)fps_idx[b * NP + s] & (NN - 1);
  const float cx = xb[ci * 3 + 0];
  const float cy = xb[ci * 3 + 1];
  const float cz = xb[ci * 3 + 2];
  const float nn = (cx * cx + cy * cy) + cz * cz;
  const float r2 = 0.04f;
  unsigned short* gout = gidx + (size_t)(b * NP + s) * NSAMP;
  int total = 0;
  int first = -1;
  for (int c = 0; c < NN / 64 && total < NSAMP; ++c) {
    int i = (c << 6) + lane;
    float x = xb[i * 3 + 0];
    float y = xb[i * 3 + 1];
    float z = xb[i * 3 + 2];
    float pp = (x * x + y * y) + z * z;
    float dt = (x * cx + y * cy) + z * cz;
    float sq = (nn + pp) - 2.0f * dt;  // exact ref formula; self-dist == 0
    bool inb = !(sq > r2);
    unsigned long long m = __ballot(inb);
    if (first < 0 && m) first = (c << 6) + (__ffsll((unsigned long long)m) - 1);
    int before = __popcll(m & ((1ull << lane) - 1ull));
    int slot = total + before;
    if (inb && slot < NSAMP) gout[slot] = (unsigned short)i;
    total += (int)__popcll(m);
  }
  int cnt = total < NSAMP ? total : NSAMP;
  unsigned short fill = (unsigned short)(first < 0 ? 0 : first);
  if (lane >= cnt && lane < NSAMP) gout[lane] = fill;
}

// ---- Kernel 3: gather + MLP(67->64->64->128) + max, k+1 register prefetch --
__global__ __launch_bounds__(256) void mlp_kernel(
    const float* __restrict__ xyz, const float* __restrict__ points,
    const unsigned short* __restrict__ fps_idx, const unsigned short* __restrict__ gidx,
    const float* __restrict__ W0, const float* __restrict__ b0,
    const float* __restrict__ g0, const float* __restrict__ be0,
    const float* __restrict__ W1, const float* __restrict__ b1,
    const float* __restrict__ g1, const float* __restrict__ be1,
    const float* __restrict__ W2, const float* __restrict__ b2,
    const float* __restrict__ g2, const float* __restrict__ be2,
    float* __restrict__ out_feat) {
  __shared__ __align__(16) float wbuf[4352];
  __shared__ __align__(16) unsigned int xpk[8 * 68 * XS];
  __shared__ float prm[768];
  const int tid = threadIdx.x;
  const float bnsc = 1.0f / sqrtf(1.001f);
  if (tid < 64) {
    prm[tid] = b0[tid];       prm[64 + tid] = g0[tid] * bnsc;  prm[128 + tid] = be0[tid];
    prm[192 + tid] = b1[tid]; prm[256 + tid] = g1[tid] * bnsc; prm[320 + tid] = be1[tid];
  }
  if (tid < 128) {
    prm[384 + tid] = b2[tid]; prm[512 + tid] = g2[tid] * bnsc; prm[640 + tid] = be2[tid];
  }
  if (tid < 128) {
    const int cbg = tid >> 4, r2 = tid & 15;
    const int sgg = blockIdx.x * 8 + cbg;
    const int bg = sgg >> 10, sg = sgg & 1023;
    const unsigned short* gi = gidx + (size_t)(bg * NP + sg) * NSAMP;
    const int i0 = (int)gi[2 * r2] & (NN - 1);
    const int i1 = (int)gi[2 * r2 + 1] & (NN - 1);
    const int ci = (int)fps_idx[bg * NP + sg] & (NN - 1);
    const float* xb = xyz + (size_t)bg * NN * 3;
    unsigned int* xc = &xpk[(cbg * 68) * XS + r2];
    const float cx = xb[ci * 3], cy = xb[ci * 3 + 1], cz = xb[ci * 3 + 2];
    xc[0 * XS] = packbf(xb[i0 * 3] - cx,     xb[i1 * 3] - cx);
    xc[1 * XS] = packbf(xb[i0 * 3 + 1] - cy, xb[i1 * 3 + 1] - cy);
    xc[2 * XS] = packbf(xb[i0 * 3 + 2] - cz, xb[i1 * 3 + 2] - cz);
    const float4* p0 = (const float4*)(points + ((size_t)bg * NN + i0) * CIN);
    const float4* p1 = (const float4*)(points + ((size_t)bg * NN + i1) * CIN);
#pragma unroll 4
    for (int kk = 0; kk < 16; ++kk) {
      float4 a = p0[kk], c = p1[kk];
      xc[(3 + 4 * kk) * XS] = packbf(a.x, c.x);
      xc[(4 + 4 * kk) * XS] = packbf(a.y, c.y);
      xc[(5 + 4 * kk) * XS] = packbf(a.z, c.z);
      xc[(6 + 4 * kk) * XS] = packbf(a.w, c.w);
    }
  } else {
    for (int i = tid - 128; i < 67 * 64; i += 128) wbuf[i] = W0[i];
  }
  const int cb = tid >> 5, rg = (tid >> 3) & 3, cg = tid & 7;
  const int sgc = blockIdx.x * 8 + cb;
  const int bc = sgc >> 10, sc = sgc & 1023;
  const unsigned int* xrow = &xpk[(cb * 68) * XS + rg * 4];
  float acc[64];
  // k-loop with one-step register prefetch (one-past-end reads are in-bounds:
  // wbuf[4352] >= 67*64+63, xpk[10880] >= (7*68+67)*20+15).
  auto kloop = [&](int K) {
    uint4 xp = *(const uint4*)(xrow);
    float4 wa = *(const float4*)&wbuf[cg * 8];
    float4 wc = *(const float4*)&wbuf[cg * 8 + 4];
#pragma unroll 2
    for (int k = 0; k < K; ++k) {
      uint4 xpn = *(const uint4*)(xrow + (k + 1) * XS);
      float4 wan = *(const float4*)&wbuf[(k + 1) * 64 + cg * 8];
      float4 wcn = *(const float4*)&wbuf[(k + 1) * 64 + cg * 8 + 4];
      float xr[8] = {lo2f(xp.x), hi2f(xp.x), lo2f(xp.y), hi2f(xp.y),
                     lo2f(xp.z), hi2f(xp.z), lo2f(xp.w), hi2f(xp.w)};
#pragma unroll
      for (int r = 0; r < 8; ++r) {
        acc[r * 8 + 0] = fmaf(xr[r], wa.x, acc[r * 8 + 0]);
        acc[r * 8 + 1] = fmaf(xr[r], wa.y, acc[r * 8 + 1]);
        acc[r * 8 + 2] = fmaf(xr[r], wa.z, acc[r * 8 + 2]);
        acc[r * 8 + 3] = fmaf(xr[r], wa.w, acc[r * 8 + 3]);
        acc[r * 8 + 4] = fmaf(xr[r], wc.x, acc[r * 8 + 4]);
        acc[r * 8 + 5] = fmaf(xr[r], wc.y, acc[r * 8 + 5]);
        acc[r * 8 + 6] = fmaf(xr[r], wc.z, acc[r * 8 + 6]);
        acc[r * 8 + 7] = fmaf(xr[r], wc.w, acc[r * 8 + 7]);
      }
      xp = xpn; wa = wan; wc = wcn;
    }
  };
  auto hwrite = [&](int pofs) {
#pragma unroll
    for (int c = 0; c < 8; ++c) {
      int cl = cg * 8 + c;
      float bia = prm[pofs + cl], gg = prm[pofs + 64 + cl], bb = prm[pofs + 128 + cl];
      unsigned int* hc = &xpk[(cb * 68 + cl) * XS + rg * 4];
#pragma unroll
      for (int i = 0; i < 4; ++i) {
        float za = acc[(2 * i) * 8 + c] + bia;
        za = za > 0.f ? za : 0.f;
        za = za * gg + bb;
        float zb = acc[(2 * i + 1) * 8 + c] + bia;
        zb = zb > 0.f ? zb : 0.f;
        zb = zb * gg + bb;
        hc[i] = packbf(za, zb);
      }
    }
  };
  __syncthreads();
#pragma unroll
  for (int i = 0; i < 64; ++i) acc[i] = 0.f;
  kloop(67);
  __syncthreads();
  hwrite(0);
  for (int i = tid; i < 64 * 64; i += 256) wbuf[i] = W1[i];
  __syncthreads();
#pragma unroll
  for (int i = 0; i < 64; ++i) acc[i] = 0.f;
  kloop(64);
  __syncthreads();
  hwrite(192);
  for (int i = tid; i < 64 * 64; i += 256) wbuf[i] = W2[(i >> 6) * C3 + (i & 63)];
  __syncthreads();
  float* outp = out_feat + (size_t)(bc * NP + sc) * C3;
#pragma unroll 1
  for (int half = 0; half < 2; ++half) {
    if (half) {
      __syncthreads();
      for (int i = tid; i < 64 * 64; i += 256)
        wbuf[i] = W2[(i >> 6) * C3 + 64 + (i & 63)];
      __syncthreads();
    }
#pragma unroll
    for (int i = 0; i < 64; ++i) acc[i] = 0.f;
    kloop(64);
    float vout[8];
#pragma unroll
    for (int c = 0; c < 8; ++c) {
      int cl = half * 64 + cg * 8 + c;
      float bia = prm[384 + cl], gg = prm[512 + cl], bb = prm[640 + cl];
      float mmax = -3.4e38f;
#pragma unroll
      for (int r = 0; r < 8; ++r) {
        float z = acc[r * 8 + c] + bia;
        z = z > 0.f ? z : 0.f;
        z = z * gg + bb;
        mmax = fmaxf(mmax, z);
      }
      mmax = fmaxf(mmax, __shfl_xor(mmax, 8, 64));
      mmax = fmaxf(mmax, __shfl_xor(mmax, 16, 64));
      vout[c] = mmax;
    }
    if (rg == 0) {
      *(float4*)(outp + half * 64 + cg * 8) =
          make_float4(vout[0], vout[1], vout[2], vout[3]);
      *(float4*)(outp + half * 64 + cg * 8 + 4) =
          make_float4(vout[4], vout[5], vout[6], vout[7]);
    }
  }
}

extern "C" void kernel_launch(void* const* d_in, const int* in_sizes, int n_in,
                              void* d_out, int out_size, void* d_ws, size_t ws_size,
                              hipStream_t stream) {
  const float* xyz = (const float*)d_in[0];
  const float* points = (const float*)d_in[1];
  const float* W0 = (const float*)d_in[2];
  const float* b0 = (const float*)d_in[3];
  const float* g0 = (const float*)d_in[4];
  const float* be0 = (const float*)d_in[5];
  const float* W1 = (const float*)d_in[6];
  const float* b1 = (const float*)d_in[7];
  const float* g1 = (const float*)d_in[8];
  const float* be1 = (const float*)d_in[9];
  const float* W2 = (const float*)d_in[10];
  const float* b2 = (const float*)d_in[11];
  const float* g2 = (const float*)d_in[12];
  const float* be2 = (const float*)d_in[13];
  float* out = (float*)d_out;
  unsigned short* fps = (unsigned short*)d_ws;                    // 16 KB
  unsigned short* gidx = fps + (size_t)NB * NP;                   // 512 KB
  unsigned int* sent = (unsigned int*)((char*)d_ws + (16 + 512) * 1024);
  fps_kernel<<<GRID1, 256, 0, stream>>>(xyz, fps, out, sent);
  ballq_kernel<<<(NB * NP) / 4, 256, 0, stream>>>(xyz, fps, gidx);
  mlp_kernel<<<NB * NP / 8, 256, 0, stream>>>(xyz, points, fps, gidx,
                                              W0, b0, g0, be0, W1, b1, g1, be1,
                                              W2, b2, g2, be2,
                                              out + (size_t)NB * NP * 3);
}